// Round 6
// baseline (823.951 us; speedup 1.0000x reference)
//
#include <hip/hip_runtime.h>
#include <math.h>
#include <stdint.h>

#define NN 50000
#define NE 800000
#define HD 64
#define ECH 32
#define NHEAD 4
#define NBLK 196   // ceil(NN/256)
#define CAP 80     // max row-span per 256-edge block handled in LDS (avg ~17)

static_assert(NE % 256 == 0, "edge kernel assumes full blocks");

typedef __attribute__((ext_vector_type(8))) short bf8;
typedef __attribute__((ext_vector_type(4))) float f32x4;

__device__ __forceinline__ float ssp_f(float v) {
    return fmaxf(v, 0.0f) + log1pf(__expf(-fabsf(v))) - 0.69314718055994531f;
}
__device__ __forceinline__ uint32_t f2bf_bits(float f) {
    uint32_t u = __float_as_uint(f);
    return (u + 0x7FFFu + ((u >> 16) & 1u)) >> 16;
}
__device__ __forceinline__ float bf2f(uint32_t b) { return __uint_as_float(b << 16); }

__device__ __forceinline__ void unpack8(uint4 p, float* o) {
    o[0] = bf2f(p.x & 0xffffu); o[1] = bf2f(p.x >> 16);
    o[2] = bf2f(p.y & 0xffffu); o[3] = bf2f(p.y >> 16);
    o[4] = bf2f(p.z & 0xffffu); o[5] = bf2f(p.z >> 16);
    o[6] = bf2f(p.w & 0xffffu); o[7] = bf2f(p.w >> 16);
}
__device__ __forceinline__ uint4 pack8u(const float* s) {
    uint4 r;
    r.x = f2bf_bits(s[0]) | (f2bf_bits(s[1]) << 16);
    r.y = f2bf_bits(s[2]) | (f2bf_bits(s[3]) << 16);
    r.z = f2bf_bits(s[4]) | (f2bf_bits(s[5]) << 16);
    r.w = f2bf_bits(s[6]) | (f2bf_bits(s[7]) << 16);
    return r;
}
__device__ __forceinline__ bf8 pack_bf8(float4 a, float4 b) {
    bf8 r;
    r[0] = (short)f2bf_bits(a.x); r[1] = (short)f2bf_bits(a.y);
    r[2] = (short)f2bf_bits(a.z); r[3] = (short)f2bf_bits(a.w);
    r[4] = (short)f2bf_bits(b.x); r[5] = (short)f2bf_bits(b.y);
    r[6] = (short)f2bf_bits(b.z); r[7] = (short)f2bf_bits(b.w);
    return r;
}
__device__ __forceinline__ bf8 zero_bf8() {
    bf8 r;
    #pragma unroll
    for (int i = 0; i < 8; ++i) r[i] = 0;
    return r;
}

// ---------------- Kernel A: node q/k/v, fold wkl into q side, bf16 outputs ----------------
__global__ __launch_bounds__(256) void node_transform_kernel(
    const float* __restrict__ x,
    const float* __restrict__ k_w, const float* __restrict__ q_w, const float* __restrict__ v_w,
    const float* __restrict__ wkl_w, const float* __restrict__ wkl_b,
    uint16_t* __restrict__ qt, float* __restrict__ qb,
    uint16_t* __restrict__ hk, uint16_t* __restrict__ hv)
{
    __shared__ float skw[NHEAD * 256], sqw[NHEAD * 256], svw[NHEAD * 256];
    __shared__ float s_kl[256], s_klb[16];
    for (int i = threadIdx.x; i < NHEAD * 256; i += 256) {
        skw[i] = k_w[i]; sqw[i] = q_w[i]; svw[i] = v_w[i];
    }
    if (threadIdx.x < 256) s_kl[threadIdx.x] = wkl_w[threadIdx.x];
    if (threadIdx.x < 16) s_klb[threadIdx.x] = wkl_b[threadIdx.x];
    __syncthreads();
    int n = blockIdx.x * 256 + threadIdx.x;
    if (n >= NN) return;
    const float* xn = x + (size_t)n * HD;
    float qbv[NHEAD];
    for (int h = 0; h < NHEAD; ++h) {
        float xr[16];
        {
            const float4* xp = (const float4*)(xn + h * 16);
            #pragma unroll
            for (int j = 0; j < 4; ++j) *(float4*)&xr[4 * j] = xp[j];
        }
        float rq[16], rk[16], rv[16];
        for (int o = 0; o < 16; ++o) {
            const float* wq = sqw + h * 256 + o * 16;
            const float* wk = skw + h * 256 + o * 16;
            const float* wv = svw + h * 256 + o * 16;
            float sq = 0.f, sk = 0.f, sv = 0.f;
            #pragma unroll
            for (int i = 0; i < 16; ++i) {
                sq += xr[i] * wq[i];
                sk += xr[i] * wk[i];
                sv += xr[i] * wv[i];
            }
            rq[o] = sq; rk[o] = sk; rv[o] = sv;
        }
        float rqt[16];
        float qbh = 0.f;
        for (int i = 0; i < 16; ++i) {
            float s = 0.f;
            #pragma unroll
            for (int o = 0; o < 16; ++o) s += rq[o] * s_kl[o * 16 + i];
            rqt[i] = s;
        }
        #pragma unroll
        for (int o = 0; o < 16; ++o) qbh += rq[o] * s_klb[o];
        qbv[h] = qbh;

        uint4* oq = (uint4*)(qt + (size_t)n * HD + h * 16);
        uint4* ok = (uint4*)(hk + (size_t)n * HD + h * 16);
        uint4* ov = (uint4*)(hv + (size_t)n * HD + h * 16);
        oq[0] = pack8u(rqt); oq[1] = pack8u(rqt + 8);
        ok[0] = pack8u(rk);  ok[1] = pack8u(rk + 8);
        ov[0] = pack8u(rv);  ov[1] = pack8u(rv + 8);
    }
    *(float4*)(qb + (size_t)n * NHEAD) = *(float4*)&qbv[0];
}

// ---------------- Count rows ----------------
__global__ __launch_bounds__(256) void count_kernel(
    const int* __restrict__ ei, int* __restrict__ counts)
{
    int e = blockIdx.x * 256 + threadIdx.x;
    if (e >= NE) return;
    atomicAdd(counts + ei[e], 1);
}

// ---------------- Hierarchical scan ----------------
__global__ __launch_bounds__(256) void scan_bsum_kernel(
    const int* __restrict__ counts, int* __restrict__ bsum)
{
    __shared__ int sd[256];
    int i = blockIdx.x * 256 + threadIdx.x;
    sd[threadIdx.x] = (i < NN) ? counts[i] : 0;
    __syncthreads();
    for (int s = 128; s > 0; s >>= 1) {
        if (threadIdx.x < (unsigned)s) sd[threadIdx.x] += sd[threadIdx.x + s];
        __syncthreads();
    }
    if (threadIdx.x == 0) bsum[blockIdx.x] = sd[0];
}

__global__ __launch_bounds__(256) void scan_top_kernel(int* __restrict__ bsum)
{
    __shared__ int tmp[256];
    int v = (threadIdx.x < NBLK) ? bsum[threadIdx.x] : 0;
    tmp[threadIdx.x] = v;
    __syncthreads();
    for (int d = 1; d < 256; d <<= 1) {
        int t = (threadIdx.x >= (unsigned)d) ? tmp[threadIdx.x - d] : 0;
        __syncthreads();
        tmp[threadIdx.x] += t;
        __syncthreads();
    }
    if (threadIdx.x < NBLK) bsum[threadIdx.x] = tmp[threadIdx.x] - v;  // exclusive
}

__global__ __launch_bounds__(256) void scan_final_kernel(
    const int* __restrict__ counts, const int* __restrict__ bsum,
    int* __restrict__ cursor)
{
    __shared__ int tmp[256];
    int i = blockIdx.x * 256 + threadIdx.x;
    int v = (i < NN) ? counts[i] : 0;
    tmp[threadIdx.x] = v;
    __syncthreads();
    for (int d = 1; d < 256; d <<= 1) {
        int t = (threadIdx.x >= (unsigned)d) ? tmp[threadIdx.x - d] : 0;
        __syncthreads();
        tmp[threadIdx.x] += t;
        __syncthreads();
    }
    int excl = tmp[threadIdx.x] - v + bsum[blockIdx.x];
    if (i < NN) cursor[i] = excl;
}

// ---------------- Scatter: (row,col) + bf16 edge_attr into CSR order ----------------
__global__ __launch_bounds__(256) void scatter_kernel(
    const int* __restrict__ ei, const float* __restrict__ ea,
    int* __restrict__ cursor,
    int2* __restrict__ rc, uint16_t* __restrict__ eaS)
{
    int e = blockIdx.x * 256 + threadIdx.x;
    if (e >= NE) return;
    int r = ei[e];
    int c = ei[NE + e];
    float eav[32];
    const float4* p = (const float4*)(ea + (size_t)e * ECH);
    #pragma unroll
    for (int i = 0; i < 8; ++i) *(float4*)&eav[4 * i] = p[i];
    int pos = atomicAdd(cursor + r, 1);
    rc[pos] = make_int2(r, c);
    uint4* d = (uint4*)(eaS + (size_t)pos * ECH);
    d[0] = pack8u(eav);      d[1] = pack8u(eav + 8);
    d[2] = pack8u(eav + 16); d[3] = pack8u(eav + 24);
}

// ---------------- Kernel B: fused edge compute + segmented aggregation ----------------
__global__ __launch_bounds__(256) void edge_fused_kernel(
    const int2* __restrict__ rc, const uint16_t* __restrict__ eaS,
    const float* __restrict__ wkn_w1, const float* __restrict__ wkn_b1,
    const float* __restrict__ wkn_w2, const float* __restrict__ wkn_b2,
    const float* __restrict__ wvn_w1, const float* __restrict__ wvn_b1,
    const float* __restrict__ wvn_w2, const float* __restrict__ wvn_b2,
    const uint16_t* __restrict__ qt, const float* __restrict__ qb,
    const uint16_t* __restrict__ hk, const uint16_t* __restrict__ hv,
    float* __restrict__ numer, float* __restrict__ denom)
{
    // s_trA/s_trB: per-wave private MFMA transposes (no barriers needed — same-wave
    // in-order DS pipe, validated R4/R5). s_trA is reused: l1k -> l1v -> Wv.
    __shared__ uint16_t s_trA[4][64][24];
    __shared__ uint16_t s_trB[4][64][24];
    // block-shared segmented accumulator: [row - r0][0:64]=numer, [64:68]=denom
    __shared__ float s_acc[CAP][68];

    // zero accumulator (block-wide, barrier before first ds_add below)
    {
        float4* az = (float4*)&s_acc[0][0];
        float4 z = {0.f, 0.f, 0.f, 0.f};
        for (int i = threadIdx.x; i < CAP * 68 / 4; i += 256) az[i] = z;
    }

    const int w = threadIdx.x >> 6;
    const int L = threadIdx.x & 63;
    const int m = L & 15;     // MFMA: A out-ch / B edge; tail: edge-within-tile
    const int g = L >> 4;     // MFMA: k-group / D row-quad; tail: head
    const int bbase = blockIdx.x * 256;
    const int ebase = bbase + w * 64;

    const int r0    = rc[bbase].x;
    const int rlast = rc[bbase + 255].x;
    const int nrows = rlast - r0 + 1;
    const bool overflow = nrows > CAP;

    int2 rcv[4];
    #pragma unroll
    for (int t = 0; t < 4; ++t) rcv[t] = rc[ebase + 16 * t + m];

    // --- edge_attr B-fragments straight from pre-sorted bf16 (coalesced 16B/lane) ---
    bf8 eaf[4];
    #pragma unroll
    for (int t = 0; t < 4; ++t)
        eaf[t] = *(const bf8*)(eaS + (size_t)(ebase + 16 * t + m) * ECH + 8 * g);

    // --- weight A-fragments ---
    bf8 w1kf, w1vf, w2kf, w2vf;
    {
        const float* p = wkn_w1 + m * 32 + 8 * g;
        w1kf = pack_bf8(*(const float4*)p, *(const float4*)(p + 4));
        p = wvn_w1 + m * 32 + 8 * g;
        w1vf = pack_bf8(*(const float4*)p, *(const float4*)(p + 4));
        if (g < 2) {
            p = wkn_w2 + m * 16 + 8 * g;
            w2kf = pack_bf8(*(const float4*)p, *(const float4*)(p + 4));
            p = wvn_w2 + m * 16 + 8 * g;
            w2vf = pack_bf8(*(const float4*)p, *(const float4*)(p + 4));
        } else {
            w2kf = zero_bf8(); w2vf = zero_bf8();
        }
    }
    float4 b1k = *(const float4*)(wkn_b1 + 4 * g);
    float4 b1v = *(const float4*)(wvn_b1 + 4 * g);
    float4 b2k = *(const float4*)(wkn_b2 + 4 * g);
    float4 b2v = *(const float4*)(wvn_b2 + 4 * g);

    // --- layer1 k-net -> s_trA; read l1k ---
    #pragma unroll
    for (int t = 0; t < 4; ++t) {
        f32x4 acc = {b1k.x, b1k.y, b1k.z, b1k.w};
        acc = __builtin_amdgcn_mfma_f32_16x16x32_bf16(w1kf, eaf[t], acc, 0, 0, 0);
        uint2 pk;
        pk.x = f2bf_bits(ssp_f(acc[0])) | (f2bf_bits(ssp_f(acc[1])) << 16);
        pk.y = f2bf_bits(ssp_f(acc[2])) | (f2bf_bits(ssp_f(acc[3])) << 16);
        *(uint2*)&s_trA[w][16 * t + m][4 * g] = pk;
    }
    bf8 l1k[4];
    #pragma unroll
    for (int t = 0; t < 4; ++t)
        l1k[t] = (g < 2) ? *(const bf8*)&s_trA[w][16 * t + m][8 * g] : zero_bf8();
    // --- layer1 v-net -> s_trA (reuse); read l1v ---
    #pragma unroll
    for (int t = 0; t < 4; ++t) {
        f32x4 acc = {b1v.x, b1v.y, b1v.z, b1v.w};
        acc = __builtin_amdgcn_mfma_f32_16x16x32_bf16(w1vf, eaf[t], acc, 0, 0, 0);
        uint2 pk;
        pk.x = f2bf_bits(ssp_f(acc[0])) | (f2bf_bits(ssp_f(acc[1])) << 16);
        pk.y = f2bf_bits(ssp_f(acc[2])) | (f2bf_bits(ssp_f(acc[3])) << 16);
        *(uint2*)&s_trA[w][16 * t + m][4 * g] = pk;
    }
    bf8 l1v[4];
    #pragma unroll
    for (int t = 0; t < 4; ++t)
        l1v[t] = (g < 2) ? *(const bf8*)&s_trA[w][16 * t + m][8 * g] : zero_bf8();

    // --- layer2: Wk -> s_trB, Wv -> s_trA ---
    #pragma unroll
    for (int t = 0; t < 4; ++t) {
        f32x4 acc = {b2k.x, b2k.y, b2k.z, b2k.w};
        acc = __builtin_amdgcn_mfma_f32_16x16x32_bf16(w2kf, l1k[t], acc, 0, 0, 0);
        uint2 pk;
        pk.x = f2bf_bits(acc[0]) | (f2bf_bits(acc[1]) << 16);
        pk.y = f2bf_bits(acc[2]) | (f2bf_bits(acc[3]) << 16);
        *(uint2*)&s_trB[w][16 * t + m][4 * g] = pk;

        f32x4 accv = {b2v.x, b2v.y, b2v.z, b2v.w};
        accv = __builtin_amdgcn_mfma_f32_16x16x32_bf16(w2vf, l1v[t], accv, 0, 0, 0);
        uint2 pv;
        pv.x = f2bf_bits(accv[0]) | (f2bf_bits(accv[1]) << 16);
        pv.y = f2bf_bits(accv[2]) | (f2bf_bits(accv[3]) << 16);
        *(uint2*)&s_trA[w][16 * t + m][4 * g] = pv;
    }

    __syncthreads();   // accumulator zeroing complete before any ds_add

    // --- tail: 4 lanes per edge; accumulate into LDS segmented accumulator ---
    #pragma unroll
    for (int t = 0; t < 4; ++t) {
        const int row = rcv[t].x, col = rcv[t].y;

        float Wk[16], Wv[16];
        unpack8(*(const uint4*)&s_trB[w][16 * t + m][0], Wk);
        unpack8(*(const uint4*)&s_trB[w][16 * t + m][8], Wk + 8);
        unpack8(*(const uint4*)&s_trA[w][16 * t + m][0], Wv);
        unpack8(*(const uint4*)&s_trA[w][16 * t + m][8], Wv + 8);

        const uint4* qp = (const uint4*)(qt + (size_t)row * HD + 16 * g);
        const uint4* kp = (const uint4*)(hk + (size_t)col * HD + 16 * g);
        const uint4* vp = (const uint4*)(hv + (size_t)col * HD + 16 * g);
        float qr[16], kc[16], vc[16];
        unpack8(qp[0], qr); unpack8(qp[1], qr + 8);
        unpack8(kp[0], kc); unpack8(kp[1], kc + 8);
        unpack8(vp[0], vc); unpack8(vp[1], vc + 8);

        float qk = qb[(size_t)row * NHEAD + g];
        #pragma unroll
        for (int i = 0; i < 16; ++i) qk += qr[i] * Wk[i] * kc[i];
        float wgt = __expf(qk);   // softmax shift-invariance

        int idx = row - r0;
        if (idx < CAP) {
            float* ar = &s_acc[idx][16 * g];
            #pragma unroll
            for (int i = 0; i < 16; ++i) atomicAdd(ar + i, wgt * Wv[i] * vc[i]);
            atomicAdd(&s_acc[idx][64 + g], wgt);
        } else {  // rare overflow: direct device-scope atomics
            float* nr = numer + (size_t)row * HD + 16 * g;
            #pragma unroll
            for (int i = 0; i < 16; ++i) atomicAdd(nr + i, wgt * Wv[i] * vc[i]);
            atomicAdd(denom + (size_t)row * NHEAD + g, wgt);
        }
    }
    __syncthreads();   // all ds_adds done before flush

    // --- flush: plain store for interior rows (block-owned), atomicAdd for
    //     boundary rows / overflow blocks. numer+denom pre-zeroed by memset. ---
    const int lim = (nrows < CAP) ? nrows : CAP;
    for (int j = threadIdx.x; j < lim * 68; j += 256) {
        int ridx = j / 68;
        int c = j - ridx * 68;
        float v = s_acc[ridx][c];
        bool at = overflow || (ridx == 0) || (ridx == lim - 1);
        float* dst = (c < 64) ? (numer + (size_t)(r0 + ridx) * HD + c)
                              : (denom + (size_t)(r0 + ridx) * NHEAD + (c - 64));
        if (at) atomicAdd(dst, v);
        else    *dst = v;
    }
}

// ---------------- Kernel F: finalize (normalize + wvl + cen + ssp + out) ----------------
__global__ __launch_bounds__(256) void finalize_kernel(
    const float* __restrict__ x,
    const float* __restrict__ numer, const float* __restrict__ denom,
    const float* __restrict__ wvl_w, const float* __restrict__ wvl_b,
    const float* __restrict__ cen_w, const float* __restrict__ cen_b,
    const float* __restrict__ out_w, const float* __restrict__ out_b,
    float* __restrict__ out)
{
    // cen/out weights TRANSPOSED in LDS (2-way bank alias = free)
    __shared__ float s_cw[4096], s_ow[4096];
    __shared__ float s_wvl[256], s_vlb[16];
    __shared__ float s_m[4][64], s_x[4][64], s_t[4][64];
    for (int idx = threadIdx.x; idx < 4096; idx += 256) {
        int o = idx & 63, i = idx >> 6;
        s_cw[i * 64 + o] = cen_w[o * 64 + i];
        s_ow[i * 64 + o] = out_w[o * 64 + i];
    }
    if (threadIdx.x < 256) s_wvl[threadIdx.x] = wvl_w[threadIdx.x];
    if (threadIdx.x < 16) s_vlb[threadIdx.x] = wvl_b[threadIdx.x];
    __syncthreads();

    int l = threadIdx.x >> 6;
    int L = threadIdx.x & 63;
    int h = L >> 4;

    for (int t = 0; t < 16; ++t) {
        int n = blockIdx.x * 64 + l * 16 + t;
        bool valid = n < NN;
        float d = valid ? denom[(size_t)n * NHEAD + h] : 0.f;
        float num = valid ? numer[(size_t)n * HD + L] : 0.f;
        bool has = d != 0.f;
        s_m[l][L] = has ? num / d : 0.f;
        s_x[l][L] = valid ? x[(size_t)n * HD + L] : 0.f;
        // s_m/s_x/s_t rows are same-wave private: no barrier needed

        float aggr = 0.f;
        if (has) {
            int o = L & 15;
            float s = s_vlb[o];
            #pragma unroll
            for (int i = 0; i < 16; ++i) s += s_m[l][h * 16 + i] * s_wvl[o * 16 + i];
            aggr = s;
        }
        float sc = cen_b[L];
        #pragma unroll 8
        for (int i = 0; i < 64; ++i) sc += s_x[l][i] * s_cw[i * 64 + L];
        sc += aggr;
        s_t[l][L] = ssp_f(sc);
        float so = out_b[L];
        #pragma unroll 8
        for (int i = 0; i < 64; ++i) so += s_t[l][i] * s_ow[i * 64 + L];
        if (valid) out[(size_t)n * HD + L] = so;
    }
}

extern "C" void kernel_launch(void* const* d_in, const int* in_sizes, int n_in,
                              void* d_out, int out_size, void* d_ws, size_t ws_size,
                              hipStream_t stream)
{
    const float* x      = (const float*)d_in[0];
    const int*   ei     = (const int*)d_in[1];
    const float* ea     = (const float*)d_in[2];
    const float* k_w    = (const float*)d_in[3];
    const float* q_w    = (const float*)d_in[4];
    const float* v_w    = (const float*)d_in[5];
    const float* wkn_w1 = (const float*)d_in[6];
    const float* wkn_b1 = (const float*)d_in[7];
    const float* wkn_w2 = (const float*)d_in[8];
    const float* wkn_b2 = (const float*)d_in[9];
    const float* wkl_w  = (const float*)d_in[10];
    const float* wkl_b  = (const float*)d_in[11];
    const float* wvn_w1 = (const float*)d_in[12];
    const float* wvn_b1 = (const float*)d_in[13];
    const float* wvn_w2 = (const float*)d_in[14];
    const float* wvn_b2 = (const float*)d_in[15];
    const float* wvl_w  = (const float*)d_in[16];
    const float* wvl_b  = (const float*)d_in[17];
    const float* cen_w  = (const float*)d_in[18];
    const float* cen_b  = (const float*)d_in[19];
    const float* out_w  = (const float*)d_in[20];
    const float* out_b  = (const float*)d_in[21];
    float* out = (float*)d_out;

    // workspace layout — numer/denom/counts contiguous for single memset
    float* numer = (float*)d_ws;                              // NN*64 f32
    float* denom = numer + (size_t)NN * HD;                   // NN*4 f32
    int* counts  = (int*)(denom + (size_t)NN * NHEAD);        // NN
    int* bsum    = counts + NN;                               // 256
    int* cursor  = bsum + 256;                                // NN
    float* qb    = (float*)(cursor + NN);                     // NN*4 f32
    uint16_t* qt = (uint16_t*)(qb + (size_t)NN * NHEAD);      // NN*64 bf16
    uint16_t* hk = qt + (size_t)NN * HD;                      // NN*64 bf16
    uint16_t* hv = hk + (size_t)NN * HD;                      // NN*64 bf16
    int2* rc     = (int2*)(hv + (size_t)NN * HD);             // NE int2
    uint16_t* eaS = (uint16_t*)(rc + (size_t)NE);             // NE*32 bf16

    size_t zero_bytes = (size_t)NN * HD * 4 + (size_t)NN * NHEAD * 4 + (size_t)NN * 4;
    hipMemsetAsync(numer, 0, zero_bytes, stream);
    node_transform_kernel<<<NBLK, 256, 0, stream>>>(
        x, k_w, q_w, v_w, wkl_w, wkl_b, qt, qb, hk, hv);
    count_kernel<<<(NE + 255) / 256, 256, 0, stream>>>(ei, counts);
    scan_bsum_kernel<<<NBLK, 256, 0, stream>>>(counts, bsum);
    scan_top_kernel<<<1, 256, 0, stream>>>(bsum);
    scan_final_kernel<<<NBLK, 256, 0, stream>>>(counts, bsum, cursor);
    scatter_kernel<<<(NE + 255) / 256, 256, 0, stream>>>(ei, ea, cursor, rc, eaS);
    edge_fused_kernel<<<NE / 256, 256, 0, stream>>>(
        rc, eaS, wkn_w1, wkn_b1, wkn_w2, wkn_b2,
        wvn_w1, wvn_b1, wvn_w2, wvn_b2,
        qt, qb, hk, hv, numer, denom);
    finalize_kernel<<<(NN + 63) / 64, 256, 0, stream>>>(
        x, numer, denom, wvl_w, wvl_b, cen_w, cen_b, out_w, out_b, out);
}

// Round 7
// 498.309 us; speedup vs baseline: 1.6535x; 1.6535x over previous
//
#include <hip/hip_runtime.h>
#include <math.h>
#include <stdint.h>

#define NN 50000
#define NE 800000
#define HD 64
#define ECH 32
#define NHEAD 4
#define NBLK 196   // ceil(NN/256)
#define NEBLK (NE / 256)

static_assert(NE % 256 == 0, "edge kernel assumes full blocks");

typedef __attribute__((ext_vector_type(8))) short bf8;
typedef __attribute__((ext_vector_type(4))) float f32x4;

__device__ __forceinline__ float ssp_f(float v) {
    return fmaxf(v, 0.0f) + log1pf(__expf(-fabsf(v))) - 0.69314718055994531f;
}
__device__ __forceinline__ uint32_t f2bf_bits(float f) {
    uint32_t u = __float_as_uint(f);
    return (u + 0x7FFFu + ((u >> 16) & 1u)) >> 16;
}
__device__ __forceinline__ float bf2f(uint32_t b) { return __uint_as_float(b << 16); }

__device__ __forceinline__ void unpack8(uint4 p, float* o) {
    o[0] = bf2f(p.x & 0xffffu); o[1] = bf2f(p.x >> 16);
    o[2] = bf2f(p.y & 0xffffu); o[3] = bf2f(p.y >> 16);
    o[4] = bf2f(p.z & 0xffffu); o[5] = bf2f(p.z >> 16);
    o[6] = bf2f(p.w & 0xffffu); o[7] = bf2f(p.w >> 16);
}
__device__ __forceinline__ uint4 pack8u(const float* s) {
    uint4 r;
    r.x = f2bf_bits(s[0]) | (f2bf_bits(s[1]) << 16);
    r.y = f2bf_bits(s[2]) | (f2bf_bits(s[3]) << 16);
    r.z = f2bf_bits(s[4]) | (f2bf_bits(s[5]) << 16);
    r.w = f2bf_bits(s[6]) | (f2bf_bits(s[7]) << 16);
    return r;
}
__device__ __forceinline__ bf8 pack_bf8(float4 a, float4 b) {
    bf8 r;
    r[0] = (short)f2bf_bits(a.x); r[1] = (short)f2bf_bits(a.y);
    r[2] = (short)f2bf_bits(a.z); r[3] = (short)f2bf_bits(a.w);
    r[4] = (short)f2bf_bits(b.x); r[5] = (short)f2bf_bits(b.y);
    r[6] = (short)f2bf_bits(b.z); r[7] = (short)f2bf_bits(b.w);
    return r;
}
__device__ __forceinline__ bf8 zero_bf8() {
    bf8 r;
    #pragma unroll
    for (int i = 0; i < 8; ++i) r[i] = 0;
    return r;
}

// ---------------- Kernel A (merged): edge count + node q/k/v transform ----------------
// qtq[n]: 72 uint16 = 64 bf16 qt | 4 f32 qb  (one 144B row -> single random stream)
// hkv[n]: 128 uint16 = 64 bf16 k | 64 bf16 v (one 256B row)
__global__ __launch_bounds__(256) void node_count_kernel(
    const float* __restrict__ x, const int* __restrict__ ei,
    const float* __restrict__ k_w, const float* __restrict__ q_w, const float* __restrict__ v_w,
    const float* __restrict__ wkl_w, const float* __restrict__ wkl_b,
    uint16_t* __restrict__ qtq, uint16_t* __restrict__ hkv,
    int* __restrict__ counts)
{
    // --- count part: every block covers 256 edges (grid = NE/256 >= NBLK) ---
    atomicAdd(counts + ei[blockIdx.x * 256 + threadIdx.x], 1);

    // --- node part: first NBLK blocks ---
    if (blockIdx.x >= NBLK) return;
    __shared__ float skw[NHEAD * 256], sqw[NHEAD * 256], svw[NHEAD * 256];
    __shared__ float s_kl[256], s_klb[16];
    for (int i = threadIdx.x; i < NHEAD * 256; i += 256) {
        skw[i] = k_w[i]; sqw[i] = q_w[i]; svw[i] = v_w[i];
    }
    if (threadIdx.x < 256) s_kl[threadIdx.x] = wkl_w[threadIdx.x];
    if (threadIdx.x < 16) s_klb[threadIdx.x] = wkl_b[threadIdx.x];
    __syncthreads();
    int n = blockIdx.x * 256 + threadIdx.x;
    if (n >= NN) return;
    const float* xn = x + (size_t)n * HD;
    uint16_t* qrow = qtq + (size_t)n * 72;
    uint16_t* kvrow = hkv + (size_t)n * 128;
    float qbv[NHEAD];
    for (int h = 0; h < NHEAD; ++h) {
        float xr[16];
        {
            const float4* xp = (const float4*)(xn + h * 16);
            #pragma unroll
            for (int j = 0; j < 4; ++j) *(float4*)&xr[4 * j] = xp[j];
        }
        float rq[16], rk[16], rv[16];
        for (int o = 0; o < 16; ++o) {
            const float* wq = sqw + h * 256 + o * 16;
            const float* wk = skw + h * 256 + o * 16;
            const float* wv = svw + h * 256 + o * 16;
            float sq = 0.f, sk = 0.f, sv = 0.f;
            #pragma unroll
            for (int i = 0; i < 16; ++i) {
                sq += xr[i] * wq[i];
                sk += xr[i] * wk[i];
                sv += xr[i] * wv[i];
            }
            rq[o] = sq; rk[o] = sk; rv[o] = sv;
        }
        float rqt[16];
        float qbh = 0.f;
        for (int i = 0; i < 16; ++i) {
            float s = 0.f;
            #pragma unroll
            for (int o = 0; o < 16; ++o) s += rq[o] * s_kl[o * 16 + i];
            rqt[i] = s;
        }
        #pragma unroll
        for (int o = 0; o < 16; ++o) qbh += rq[o] * s_klb[o];
        qbv[h] = qbh;

        uint4* oq = (uint4*)(qrow + h * 16);
        uint4* ok = (uint4*)(kvrow + h * 16);
        uint4* ov = (uint4*)(kvrow + 64 + h * 16);
        oq[0] = pack8u(rqt); oq[1] = pack8u(rqt + 8);
        ok[0] = pack8u(rk);  ok[1] = pack8u(rk + 8);
        ov[0] = pack8u(rv);  ov[1] = pack8u(rv + 8);
    }
    *(float4*)(qrow + 64) = *(float4*)&qbv[0];
}

// ---------------- Hierarchical scan ----------------
__global__ __launch_bounds__(256) void scan_bsum_kernel(
    const int* __restrict__ counts, int* __restrict__ bsum)
{
    __shared__ int sd[256];
    int i = blockIdx.x * 256 + threadIdx.x;
    sd[threadIdx.x] = (i < NN) ? counts[i] : 0;
    __syncthreads();
    for (int s = 128; s > 0; s >>= 1) {
        if (threadIdx.x < (unsigned)s) sd[threadIdx.x] += sd[threadIdx.x + s];
        __syncthreads();
    }
    if (threadIdx.x == 0) bsum[blockIdx.x] = sd[0];
}

__global__ __launch_bounds__(256) void scan_top_kernel(int* __restrict__ bsum)
{
    __shared__ int tmp[256];
    int v = (threadIdx.x < NBLK) ? bsum[threadIdx.x] : 0;
    tmp[threadIdx.x] = v;
    __syncthreads();
    for (int d = 1; d < 256; d <<= 1) {
        int t = (threadIdx.x >= (unsigned)d) ? tmp[threadIdx.x - d] : 0;
        __syncthreads();
        tmp[threadIdx.x] += t;
        __syncthreads();
    }
    if (threadIdx.x < NBLK) bsum[threadIdx.x] = tmp[threadIdx.x] - v;  // exclusive
}

__global__ __launch_bounds__(256) void scan_final_kernel(
    const int* __restrict__ counts, const int* __restrict__ bsum,
    int* __restrict__ offsets, int* __restrict__ cursor)
{
    __shared__ int tmp[256];
    int i = blockIdx.x * 256 + threadIdx.x;
    int v = (i < NN) ? counts[i] : 0;
    tmp[threadIdx.x] = v;
    __syncthreads();
    for (int d = 1; d < 256; d <<= 1) {
        int t = (threadIdx.x >= (unsigned)d) ? tmp[threadIdx.x - d] : 0;
        __syncthreads();
        tmp[threadIdx.x] += t;
        __syncthreads();
    }
    int excl = tmp[threadIdx.x] - v + bsum[blockIdx.x];
    if (i < NN) { offsets[i] = excl; cursor[i] = excl; }
}

// ---------------- Scatter: edge ids + (row,col) into CSR order ----------------
__global__ __launch_bounds__(256) void scatter_kernel(
    const int* __restrict__ ei, int* __restrict__ cursor,
    int* __restrict__ elist, int2* __restrict__ rc)
{
    int e = blockIdx.x * 256 + threadIdx.x;
    if (e >= NE) return;
    int r = ei[e];
    int c = ei[NE + e];
    int pos = atomicAdd(cursor + r, 1);
    elist[pos] = e;
    rc[pos] = make_int2(r, c);
}

// ---------------- Kernel B: edge compute, MFMA MLPs, 4-lanes-per-edge tail ----------------
__global__ __launch_bounds__(256) void edge_compute_kernel(
    const int* __restrict__ elist, const int2* __restrict__ rc,
    const float* __restrict__ ea,
    const float* __restrict__ wkn_w1, const float* __restrict__ wkn_b1,
    const float* __restrict__ wkn_w2, const float* __restrict__ wkn_b2,
    const float* __restrict__ wvn_w1, const float* __restrict__ wvn_b1,
    const float* __restrict__ wvn_w2, const float* __restrict__ wvn_b2,
    const uint16_t* __restrict__ qtq, const uint16_t* __restrict__ hkv,
    uint16_t* __restrict__ payload, float* __restrict__ wfac)
{
    // per-wave PRIVATE LDS, no barriers (same-wave in-order DS pipe, validated R4-R6).
    // s_trA reused: l1k -> l1v -> Wv (R6-validated). 24.6KB total -> 6 blocks/CU.
    __shared__ uint16_t s_trA[4][64][24];
    __shared__ uint16_t s_trB[4][64][24];

    const int w = threadIdx.x >> 6;
    const int L = threadIdx.x & 63;
    const int m = L & 15;     // MFMA: A out-ch / B edge; tail: edge-within-tile
    const int g = L >> 4;     // MFMA: k-group; tail: head
    const int ebase = blockIdx.x * 256 + w * 64;

    // prefetch edge ids + (row,col) for the 4 tiles
    int eidv[4];
    int2 rcv[4];
    #pragma unroll
    for (int t = 0; t < 4; ++t) eidv[t] = elist[ebase + 16 * t + m];
    #pragma unroll
    for (int t = 0; t < 4; ++t) rcv[t] = rc[ebase + 16 * t + m];

    // --- stage edge_attr B-fragments: B[k=8g+j][n=m] = ea[edge 16t+m][8g+j] ---
    bf8 eaf[4];
    #pragma unroll
    for (int t = 0; t < 4; ++t) {
        const float* er = ea + (size_t)eidv[t] * ECH + 8 * g;
        eaf[t] = pack_bf8(*(const float4*)er, *(const float4*)(er + 4));
    }
    // --- weight A-fragments ---
    bf8 w1kf, w1vf, w2kf, w2vf;
    {
        const float* p = wkn_w1 + m * 32 + 8 * g;
        w1kf = pack_bf8(*(const float4*)p, *(const float4*)(p + 4));
        p = wvn_w1 + m * 32 + 8 * g;
        w1vf = pack_bf8(*(const float4*)p, *(const float4*)(p + 4));
        if (g < 2) {
            p = wkn_w2 + m * 16 + 8 * g;
            w2kf = pack_bf8(*(const float4*)p, *(const float4*)(p + 4));
            p = wvn_w2 + m * 16 + 8 * g;
            w2vf = pack_bf8(*(const float4*)p, *(const float4*)(p + 4));
        } else {
            w2kf = zero_bf8(); w2vf = zero_bf8();
        }
    }
    float4 b1k = *(const float4*)(wkn_b1 + 4 * g);
    float4 b1v = *(const float4*)(wvn_b1 + 4 * g);
    float4 b2k = *(const float4*)(wkn_b2 + 4 * g);
    float4 b2v = *(const float4*)(wvn_b2 + 4 * g);

    // --- layer1 k-net -> s_trA; read l1k ---
    #pragma unroll
    for (int t = 0; t < 4; ++t) {
        f32x4 acc = {b1k.x, b1k.y, b1k.z, b1k.w};
        acc = __builtin_amdgcn_mfma_f32_16x16x32_bf16(w1kf, eaf[t], acc, 0, 0, 0);
        uint2 pk;
        pk.x = f2bf_bits(ssp_f(acc[0])) | (f2bf_bits(ssp_f(acc[1])) << 16);
        pk.y = f2bf_bits(ssp_f(acc[2])) | (f2bf_bits(ssp_f(acc[3])) << 16);
        *(uint2*)&s_trA[w][16 * t + m][4 * g] = pk;
    }
    bf8 l1k[4];
    #pragma unroll
    for (int t = 0; t < 4; ++t)
        l1k[t] = (g < 2) ? *(const bf8*)&s_trA[w][16 * t + m][8 * g] : zero_bf8();
    // --- layer1 v-net -> s_trA (reuse); read l1v ---
    #pragma unroll
    for (int t = 0; t < 4; ++t) {
        f32x4 acc = {b1v.x, b1v.y, b1v.z, b1v.w};
        acc = __builtin_amdgcn_mfma_f32_16x16x32_bf16(w1vf, eaf[t], acc, 0, 0, 0);
        uint2 pk;
        pk.x = f2bf_bits(ssp_f(acc[0])) | (f2bf_bits(ssp_f(acc[1])) << 16);
        pk.y = f2bf_bits(ssp_f(acc[2])) | (f2bf_bits(ssp_f(acc[3])) << 16);
        *(uint2*)&s_trA[w][16 * t + m][4 * g] = pk;
    }
    bf8 l1v[4];
    #pragma unroll
    for (int t = 0; t < 4; ++t)
        l1v[t] = (g < 2) ? *(const bf8*)&s_trA[w][16 * t + m][8 * g] : zero_bf8();

    // --- layer2: Wk -> s_trB, Wv -> s_trA ---
    #pragma unroll
    for (int t = 0; t < 4; ++t) {
        f32x4 acc = {b2k.x, b2k.y, b2k.z, b2k.w};
        acc = __builtin_amdgcn_mfma_f32_16x16x32_bf16(w2kf, l1k[t], acc, 0, 0, 0);
        uint2 pk;
        pk.x = f2bf_bits(acc[0]) | (f2bf_bits(acc[1]) << 16);
        pk.y = f2bf_bits(acc[2]) | (f2bf_bits(acc[3]) << 16);
        *(uint2*)&s_trB[w][16 * t + m][4 * g] = pk;

        f32x4 accv = {b2v.x, b2v.y, b2v.z, b2v.w};
        accv = __builtin_amdgcn_mfma_f32_16x16x32_bf16(w2vf, l1v[t], accv, 0, 0, 0);
        uint2 pv;
        pv.x = f2bf_bits(accv[0]) | (f2bf_bits(accv[1]) << 16);
        pv.y = f2bf_bits(accv[2]) | (f2bf_bits(accv[3]) << 16);
        *(uint2*)&s_trA[w][16 * t + m][4 * g] = pv;
    }

    // --- tail: 4 lanes per edge. Lane (g,m) = head g of edge 16t+m.
    //     TWO random streams per edge (qtq 144B row, hkv 256B row) instead of
    //     R5's four (qt,qb,hk,hv) — kills the qb scalar-sector overfetch.
    #pragma unroll
    for (int t = 0; t < 4; ++t) {
        const int E = ebase + 16 * t + m;
        const int row = rcv[t].x, col = rcv[t].y;

        float Wk[16], Wv[16];
        unpack8(*(const uint4*)&s_trB[w][16 * t + m][0], Wk);
        unpack8(*(const uint4*)&s_trB[w][16 * t + m][8], Wk + 8);
        unpack8(*(const uint4*)&s_trA[w][16 * t + m][0], Wv);
        unpack8(*(const uint4*)&s_trA[w][16 * t + m][8], Wv + 8);

        const uint16_t* qrow = qtq + (size_t)row * 72;
        const uint16_t* kvrow = hkv + (size_t)col * 128;
        const uint4* qp = (const uint4*)(qrow + 16 * g);
        const uint4* kp = (const uint4*)(kvrow + 16 * g);
        const uint4* vp = (const uint4*)(kvrow + 64 + 16 * g);
        float qr[16], kc[16], vc[16];
        unpack8(qp[0], qr); unpack8(qp[1], qr + 8);
        unpack8(kp[0], kc); unpack8(kp[1], kc + 8);
        unpack8(vp[0], vc); unpack8(vp[1], vc + 8);

        float qk = *(const float*)(qrow + 64 + 2 * g);   // qb folded into qt row
        #pragma unroll
        for (int i = 0; i < 16; ++i) qk += qr[i] * Wk[i] * kc[i];
        float wgt = __expf(qk);   // softmax shift-invariance

        float o[16];
        #pragma unroll
        for (int i = 0; i < 16; ++i) o[i] = wgt * Wv[i] * vc[i];
        uint4* pd = (uint4*)(payload + (size_t)E * HD + 16 * g);
        pd[0] = pack8u(o);
        pd[1] = pack8u(o + 8);
        wfac[(size_t)E * NHEAD + g] = wgt;   // contiguous 256B per instr
    }
}

// ---------------- Kernel E: streaming gather (8-edge groups) + finalize ----------------
__global__ __launch_bounds__(256) void gather_finalize_kernel(
    const float* __restrict__ x,
    const uint16_t* __restrict__ payload, const float* __restrict__ wfac,
    const int* __restrict__ offsets, const int* __restrict__ counts,
    const float* __restrict__ wvl_w, const float* __restrict__ wvl_b,
    const float* __restrict__ cen_w, const float* __restrict__ cen_b,
    const float* __restrict__ out_w, const float* __restrict__ out_b,
    float* __restrict__ out)
{
    __shared__ float s_cw[4096], s_ow[4096];
    __shared__ float s_wvl[256], s_vlb[16];
    __shared__ float s_m[4][64], s_x[4][64], s_t[4][64];
    for (int idx = threadIdx.x; idx < 4096; idx += 256) {
        int o = idx & 63, i = idx >> 6;
        s_cw[i * 64 + o] = cen_w[o * 64 + i];
        s_ow[i * 64 + o] = out_w[o * 64 + i];
    }
    if (threadIdx.x < 256) s_wvl[threadIdx.x] = wvl_w[threadIdx.x];
    if (threadIdx.x < 16) s_vlb[threadIdx.x] = wvl_b[threadIdx.x];
    __syncthreads();

    int l = threadIdx.x >> 6;   // wave id
    int L = threadIdx.x & 63;   // lane
    int q = L & 7;              // channel octet
    int g = L >> 3;             // edge group 0..7
    int h = q >> 1;             // head owning the octet

    // wave-cooperative prefetch of offsets/counts for this wave's 16 nodes
    int n0 = blockIdx.x * 64 + l * 16;
    int pj = n0 + (L & 15);
    bool pvalid = pj < NN;
    int offv = 0, cntv = 0;
    if (L < 16) offv = pvalid ? offsets[pj] : 0;
    else if (L < 32) cntv = pvalid ? counts[pj] : 0;

    for (int t = 0; t < 16; ++t) {
        int n = n0 + t;
        bool valid = n < NN;
        int st = __shfl(offv, t);
        int deg = valid ? __shfl(cntv, 16 + t) : 0;
        float u[8] = {0.f, 0.f, 0.f, 0.f, 0.f, 0.f, 0.f, 0.f};
        float ds = 0.f;
        const uint16_t* pp = payload + (size_t)st * HD + 8 * q;
        const float* wp = wfac + (size_t)st * NHEAD + h;
        int iters = (deg + 7) >> 3;
        for (int i = 0; i < iters; ++i) {
            int e = 8 * i + g;
            if (e < deg) {
                uint4 pv = *(const uint4*)(pp + (size_t)e * HD);  // 8 edges x 128B per wave-instr
                u[0] += bf2f(pv.x & 0xffffu); u[1] += bf2f(pv.x >> 16);
                u[2] += bf2f(pv.y & 0xffffu); u[3] += bf2f(pv.y >> 16);
                u[4] += bf2f(pv.z & 0xffffu); u[5] += bf2f(pv.z >> 16);
                u[6] += bf2f(pv.w & 0xffffu); u[7] += bf2f(pv.w >> 16);
                ds += wp[(size_t)e * NHEAD];
            }
        }
        // reduce over 8 edge-groups (xor lane bits 3,4,5)
        #pragma unroll
        for (int s = 8; s < 64; s <<= 1) {
            #pragma unroll
            for (int j = 0; j < 8; ++j) u[j] += __shfl_xor(u[j], s);
            ds += __shfl_xor(ds, s);
        }
        if (g == 0) {
            float inv = (deg > 0) ? (1.f / ds) : 0.f;
            float r0[4] = {u[0] * inv, u[1] * inv, u[2] * inv, u[3] * inv};
            float r1[4] = {u[4] * inv, u[5] * inv, u[6] * inv, u[7] * inv};
            *(float4*)&s_m[l][8 * q] = *(float4*)r0;
            *(float4*)&s_m[l][8 * q + 4] = *(float4*)r1;
        }
        s_x[l][L] = valid ? x[(size_t)n * HD + L] : 0.f;
        // s_m/s_x/s_t rows are same-wave private: no __syncthreads needed

        int c = L, hh = c >> 4;
        float aggr = 0.f;
        if (deg > 0) {
            int o = c & 15;
            float s = s_vlb[o];
            #pragma unroll
            for (int i = 0; i < 16; ++i) s += s_m[l][hh * 16 + i] * s_wvl[o * 16 + i];
            aggr = s;
        }
        float sc = cen_b[c];
        #pragma unroll 8
        for (int i = 0; i < 64; ++i) sc += s_x[l][i] * s_cw[i * 64 + c];
        sc += aggr;
        s_t[l][c] = ssp_f(sc);
        float so = out_b[c];
        #pragma unroll 8
        for (int i = 0; i < 64; ++i) so += s_t[l][i] * s_ow[i * 64 + c];
        if (valid) out[(size_t)n * HD + c] = so;
    }
}

extern "C" void kernel_launch(void* const* d_in, const int* in_sizes, int n_in,
                              void* d_out, int out_size, void* d_ws, size_t ws_size,
                              hipStream_t stream)
{
    const float* x      = (const float*)d_in[0];
    const int*   ei     = (const int*)d_in[1];
    const float* ea     = (const float*)d_in[2];
    const float* k_w    = (const float*)d_in[3];
    const float* q_w    = (const float*)d_in[4];
    const float* v_w    = (const float*)d_in[5];
    const float* wkn_w1 = (const float*)d_in[6];
    const float* wkn_b1 = (const float*)d_in[7];
    const float* wkn_w2 = (const float*)d_in[8];
    const float* wkn_b2 = (const float*)d_in[9];
    const float* wkl_w  = (const float*)d_in[10];
    const float* wkl_b  = (const float*)d_in[11];
    const float* wvn_w1 = (const float*)d_in[12];
    const float* wvn_b1 = (const float*)d_in[13];
    const float* wvn_w2 = (const float*)d_in[14];
    const float* wvn_b2 = (const float*)d_in[15];
    const float* wvl_w  = (const float*)d_in[16];
    const float* wvl_b  = (const float*)d_in[17];
    const float* cen_w  = (const float*)d_in[18];
    const float* cen_b  = (const float*)d_in[19];
    const float* out_w  = (const float*)d_in[20];
    const float* out_b  = (const float*)d_in[21];
    float* out = (float*)d_out;

    // workspace layout
    float* wfac  = (float*)d_ws;                              // NE*4 f32
    uint16_t* qtq = (uint16_t*)(wfac + (size_t)NE * NHEAD);   // NN*72 (qt bf16 | qb f32)
    uint16_t* hkv = qtq + (size_t)NN * 72;                    // NN*128 (k|v bf16)
    uint16_t* payload = hkv + (size_t)NN * 128;               // NE*64 bf16
    int2* rc     = (int2*)(payload + (size_t)NE * HD);        // NE int2
    int* elist   = (int*)(rc + (size_t)NE);                   // NE
    int* counts  = elist + NE;                                // NN
    int* bsum    = counts + NN;                               // 256
    int* offsets = bsum + 256;                                // NN
    int* cursor  = offsets + NN;                              // NN

    hipMemsetAsync(counts, 0, (size_t)NN * sizeof(int), stream);
    node_count_kernel<<<NEBLK, 256, 0, stream>>>(
        x, ei, k_w, q_w, v_w, wkl_w, wkl_b, qtq, hkv, counts);
    scan_bsum_kernel<<<NBLK, 256, 0, stream>>>(counts, bsum);
    scan_top_kernel<<<1, 256, 0, stream>>>(bsum);
    scan_final_kernel<<<NBLK, 256, 0, stream>>>(counts, bsum, offsets, cursor);
    scatter_kernel<<<NEBLK, 256, 0, stream>>>(ei, cursor, elist, rc);
    edge_compute_kernel<<<NEBLK, 256, 0, stream>>>(
        elist, rc, ea, wkn_w1, wkn_b1, wkn_w2, wkn_b2,
        wvn_w1, wvn_b1, wvn_w2, wvn_b2,
        qtq, hkv, payload, wfac);
    gather_finalize_kernel<<<(NN + 63) / 64, 256, 0, stream>>>(
        x, payload, wfac, offsets, counts,
        wvl_w, wvl_b, cen_w, cen_b, out_w, out_b, out);
}